// Round 6
// baseline (354.013 us; speedup 1.0000x reference)
//
#include <hip/hip_runtime.h>

#define CC 128          // channels
#define BSEG 16         // segments
#define EPSV 1e-5f
#define ROWS_PER_BLOCK 512
#define NORM_GRID 2048

// Native clang vector (valid for __builtin_nontemporal_store, unlike HIP float4).
typedef float v4f __attribute__((ext_vector_type(4)));

// ---------------------------------------------------------------------------
// Kernel 1: per-segment per-channel sum / sumsq / count.  (unchanged from R5)
// Block owns ROWS_PER_BLOCK contiguous rows, FORWARD traversal (leaves the
// tail of x freshest in L3 for the reverse-order normalize pass).
// ---------------------------------------------------------------------------
__global__ __launch_bounds__(256) void ms_stats(const float* __restrict__ x,
                                                const int* __restrict__ bidx,
                                                int n,
                                                float* __restrict__ sum,
                                                float* __restrict__ sumsq,
                                                float* __restrict__ cnt)
{
    const int r0 = blockIdx.x * ROWS_PER_BLOCK;
    if (r0 >= n) return;
    const int rend = min(r0 + ROWS_PER_BLOCK, n);
    const int tq = threadIdx.x & 31;   // channel quad 0..31
    const int tr = threadIdx.x >> 5;   // row lane 0..7

    const int seg_first = bidx[r0];
    const int seg_last  = bidx[rend - 1];

    v4f s = {0.f, 0.f, 0.f, 0.f};
    v4f q = {0.f, 0.f, 0.f, 0.f};

    if (seg_first == seg_last) {
        int r = r0 + tr;
        for (; r + 8 < rend; r += 16) {
            const v4f a = *reinterpret_cast<const v4f*>(x + (size_t)r * CC + tq * 4);
            const v4f b = *reinterpret_cast<const v4f*>(x + (size_t)(r + 8) * CC + tq * 4);
            s += a; q += a * a;
            s += b; q += b * b;
        }
        if (r < rend) {
            const v4f a = *reinterpret_cast<const v4f*>(x + (size_t)r * CC + tq * 4);
            s += a; q += a * a;
        }
        __shared__ float red[8][8][32];
        red[tr][0][tq] = s.x; red[tr][1][tq] = s.y; red[tr][2][tq] = s.z; red[tr][3][tq] = s.w;
        red[tr][4][tq] = q.x; red[tr][5][tq] = q.y; red[tr][6][tq] = q.z; red[tr][7][tq] = q.w;
        __syncthreads();
        const int j = threadIdx.x >> 5;   // slot 0..7 (0-3 sum, 4-7 sumsq)
        float acc = 0.f;
        #pragma unroll
        for (int k = 0; k < 8; ++k) acc += red[k][j][tq];
        const int ch = tq * 4 + (j & 3);
        atomicAdd(((j < 4) ? sum : sumsq) + seg_first * CC + ch, acc);
        if (threadIdx.x == 0)
            atomicAdd(cnt + seg_first, (float)(rend - r0));
    } else {
        int cur = -1;
        float rows = 0.f;
        for (int r = r0 + tr; r < rend; r += 8) {
            const int seg = bidx[r];
            if (seg != cur) {
                if (cur >= 0) {
                    float* sd = sum   + cur * CC + tq * 4;
                    float* qd = sumsq + cur * CC + tq * 4;
                    atomicAdd(sd + 0, s.x); atomicAdd(sd + 1, s.y);
                    atomicAdd(sd + 2, s.z); atomicAdd(sd + 3, s.w);
                    atomicAdd(qd + 0, q.x); atomicAdd(qd + 1, q.y);
                    atomicAdd(qd + 2, q.z); atomicAdd(qd + 3, q.w);
                    if (tq == 0) atomicAdd(cnt + cur, rows);
                    s = (v4f){0.f, 0.f, 0.f, 0.f};
                    q = (v4f){0.f, 0.f, 0.f, 0.f};
                    rows = 0.f;
                }
                cur = seg;
            }
            const v4f a = *reinterpret_cast<const v4f*>(x + (size_t)r * CC + tq * 4);
            s += a; q += a * a;
            rows += 1.f;
        }
        if (cur >= 0) {
            float* sd = sum   + cur * CC + tq * 4;
            float* qd = sumsq + cur * CC + tq * 4;
            atomicAdd(sd + 0, s.x); atomicAdd(sd + 1, s.y);
            atomicAdd(sd + 2, s.z); atomicAdd(sd + 3, s.w);
            atomicAdd(qd + 0, q.x); atomicAdd(qd + 1, q.y);
            atomicAdd(qd + 2, q.z); atomicAdd(qd + 3, q.w);
            if (tq == 0) atomicAdd(cnt + cur, rows);
        }
    }
}

// ---------------------------------------------------------------------------
// Kernel 2: normalize. R3 structure (reverse grid-stride sweep, fused
// finalize into LDS tables, NT stores) + deep memory-level parallelism:
// each thread handles a 32B "pair" (2 x dwordx4) per sub-iteration, unrolled
// x4 with all bidx / x loads issued before any consumption -> 128B in flight
// per thread (~4KB/CU), enough to cover HBM latency at ~10B/cy/CU.
// ---------------------------------------------------------------------------
__global__ __launch_bounds__(256) void ms_norm(const float* __restrict__ x,
                                               const int* __restrict__ bidx,
                                               const float* __restrict__ sum,
                                               const float* __restrict__ sumsq,
                                               const float* __restrict__ cnt,
                                               const float* __restrict__ w,
                                               const float* __restrict__ bias,
                                               float* __restrict__ out,
                                               int n)
{
    __shared__ v4f s_scale[BSEG * 32];   // [seg][channel-quad]
    __shared__ v4f s_shift[BSEG * 32];
    for (int i = threadIdx.x; i < BSEG * CC; i += 256) {
        const int b = i >> 7;          // CC == 128
        const int c = i & (CC - 1);
        const float nn   = fmaxf(cnt[b], 1.0f);
        const float mean = sum[i] / nn;
        const float var  = fmaxf(sumsq[i] / nn - mean * mean, 0.0f);
        const float sc   = rsqrtf(var + EPSV) * w[c];
        reinterpret_cast<float*>(s_scale)[i] = sc;
        reinterpret_cast<float*>(s_shift)[i] = fmaf(-mean, sc, bias[c]);
    }
    __syncthreads();

    const int total = n * 16;                        // pairs (32B units), 16M < 2^31
    const int T     = (int)(gridDim.x * blockDim.x); // grid threads = pair stride

    // Descending sweep: whole grid marches a compact window from tail to head.
    int p = total - 1 - (int)(blockIdx.x * blockDim.x + threadIdx.x);

    // Full 4-deep supersteps.
    for (; p >= 3 * T; p -= 4 * T) {
        const int p0 = p, p1 = p - T, p2 = p - 2 * T, p3 = p - 3 * T;
        // Issue all index loads, then all data loads.
        const int g0 = bidx[p0 >> 4];
        const int g1 = bidx[p1 >> 4];
        const int g2 = bidx[p2 >> 4];
        const int g3 = bidx[p3 >> 4];
        const v4f a0 = reinterpret_cast<const v4f*>(x)[2 * (size_t)p0];
        const v4f b0 = reinterpret_cast<const v4f*>(x)[2 * (size_t)p0 + 1];
        const v4f a1 = reinterpret_cast<const v4f*>(x)[2 * (size_t)p1];
        const v4f b1 = reinterpret_cast<const v4f*>(x)[2 * (size_t)p1 + 1];
        const v4f a2 = reinterpret_cast<const v4f*>(x)[2 * (size_t)p2];
        const v4f b2 = reinterpret_cast<const v4f*>(x)[2 * (size_t)p2 + 1];
        const v4f a3 = reinterpret_cast<const v4f*>(x)[2 * (size_t)p3];
        const v4f b3 = reinterpret_cast<const v4f*>(x)[2 * (size_t)p3 + 1];

        {
            const int q2i = (p0 & 15) * 2;
            const v4f sca = s_scale[g0 * 32 + q2i], scb = s_scale[g0 * 32 + q2i + 1];
            const v4f sha = s_shift[g0 * 32 + q2i], shb = s_shift[g0 * 32 + q2i + 1];
            v4f oa, ob;
            oa.x = fmaf(a0.x, sca.x, sha.x); oa.y = fmaf(a0.y, sca.y, sha.y);
            oa.z = fmaf(a0.z, sca.z, sha.z); oa.w = fmaf(a0.w, sca.w, sha.w);
            ob.x = fmaf(b0.x, scb.x, shb.x); ob.y = fmaf(b0.y, scb.y, shb.y);
            ob.z = fmaf(b0.z, scb.z, shb.z); ob.w = fmaf(b0.w, scb.w, shb.w);
            __builtin_nontemporal_store(oa, reinterpret_cast<v4f*>(out) + 2 * (size_t)p0);
            __builtin_nontemporal_store(ob, reinterpret_cast<v4f*>(out) + 2 * (size_t)p0 + 1);
        }
        {
            const int q2i = (p1 & 15) * 2;
            const v4f sca = s_scale[g1 * 32 + q2i], scb = s_scale[g1 * 32 + q2i + 1];
            const v4f sha = s_shift[g1 * 32 + q2i], shb = s_shift[g1 * 32 + q2i + 1];
            v4f oa, ob;
            oa.x = fmaf(a1.x, sca.x, sha.x); oa.y = fmaf(a1.y, sca.y, sha.y);
            oa.z = fmaf(a1.z, sca.z, sha.z); oa.w = fmaf(a1.w, sca.w, sha.w);
            ob.x = fmaf(b1.x, scb.x, shb.x); ob.y = fmaf(b1.y, scb.y, shb.y);
            ob.z = fmaf(b1.z, scb.z, shb.z); ob.w = fmaf(b1.w, scb.w, shb.w);
            __builtin_nontemporal_store(oa, reinterpret_cast<v4f*>(out) + 2 * (size_t)p1);
            __builtin_nontemporal_store(ob, reinterpret_cast<v4f*>(out) + 2 * (size_t)p1 + 1);
        }
        {
            const int q2i = (p2 & 15) * 2;
            const v4f sca = s_scale[g2 * 32 + q2i], scb = s_scale[g2 * 32 + q2i + 1];
            const v4f sha = s_shift[g2 * 32 + q2i], shb = s_shift[g2 * 32 + q2i + 1];
            v4f oa, ob;
            oa.x = fmaf(a2.x, sca.x, sha.x); oa.y = fmaf(a2.y, sca.y, sha.y);
            oa.z = fmaf(a2.z, sca.z, sha.z); oa.w = fmaf(a2.w, sca.w, sha.w);
            ob.x = fmaf(b2.x, scb.x, shb.x); ob.y = fmaf(b2.y, scb.y, shb.y);
            ob.z = fmaf(b2.z, scb.z, shb.z); ob.w = fmaf(b2.w, scb.w, shb.w);
            __builtin_nontemporal_store(oa, reinterpret_cast<v4f*>(out) + 2 * (size_t)p2);
            __builtin_nontemporal_store(ob, reinterpret_cast<v4f*>(out) + 2 * (size_t)p2 + 1);
        }
        {
            const int q2i = (p3 & 15) * 2;
            const v4f sca = s_scale[g3 * 32 + q2i], scb = s_scale[g3 * 32 + q2i + 1];
            const v4f sha = s_shift[g3 * 32 + q2i], shb = s_shift[g3 * 32 + q2i + 1];
            v4f oa, ob;
            oa.x = fmaf(a3.x, sca.x, sha.x); oa.y = fmaf(a3.y, sca.y, sha.y);
            oa.z = fmaf(a3.z, sca.z, sha.z); oa.w = fmaf(a3.w, sca.w, sha.w);
            ob.x = fmaf(b3.x, scb.x, shb.x); ob.y = fmaf(b3.y, scb.y, shb.y);
            ob.z = fmaf(b3.z, scb.z, shb.z); ob.w = fmaf(b3.w, scb.w, shb.w);
            __builtin_nontemporal_store(oa, reinterpret_cast<v4f*>(out) + 2 * (size_t)p3);
            __builtin_nontemporal_store(ob, reinterpret_cast<v4f*>(out) + 2 * (size_t)p3 + 1);
        }
    }

    // Tail (at most 3 sub-iterations per thread).
    for (; p >= 0; p -= T) {
        const int g = bidx[p >> 4];
        const v4f a = reinterpret_cast<const v4f*>(x)[2 * (size_t)p];
        const v4f b = reinterpret_cast<const v4f*>(x)[2 * (size_t)p + 1];
        const int q2i = (p & 15) * 2;
        const v4f sca = s_scale[g * 32 + q2i], scb = s_scale[g * 32 + q2i + 1];
        const v4f sha = s_shift[g * 32 + q2i], shb = s_shift[g * 32 + q2i + 1];
        v4f oa, ob;
        oa.x = fmaf(a.x, sca.x, sha.x); oa.y = fmaf(a.y, sca.y, sha.y);
        oa.z = fmaf(a.z, sca.z, sha.z); oa.w = fmaf(a.w, sca.w, sha.w);
        ob.x = fmaf(b.x, scb.x, shb.x); ob.y = fmaf(b.y, scb.y, shb.y);
        ob.z = fmaf(b.z, scb.z, shb.z); ob.w = fmaf(b.w, scb.w, shb.w);
        __builtin_nontemporal_store(oa, reinterpret_cast<v4f*>(out) + 2 * (size_t)p);
        __builtin_nontemporal_store(ob, reinterpret_cast<v4f*>(out) + 2 * (size_t)p + 1);
    }
}

// ---------------------------------------------------------------------------
extern "C" void kernel_launch(void* const* d_in, const int* in_sizes, int n_in,
                              void* d_out, int out_size, void* d_ws, size_t ws_size,
                              hipStream_t stream)
{
    const float* x    = (const float*)d_in[0];
    const int*   bidx = (const int*)d_in[1];
    const float* w    = (const float*)d_in[2];
    const float* bias = (const float*)d_in[3];
    float* out = (float*)d_out;
    const int n = in_sizes[1];   // number of rows (batch_idx length)

    // Workspace layout (floats): sum[B*C] | sumsq[B*C] | cnt[B]
    float* ws    = (float*)d_ws;
    float* sum   = ws;
    float* sumsq = ws + BSEG * CC;
    float* cnt   = ws + 2 * BSEG * CC;

    // Zero the accumulators (ws is poisoned; must be replay-safe).
    (void)hipMemsetAsync(d_ws, 0, (size_t)(2 * BSEG * CC + BSEG) * sizeof(float), stream);

    const int g1 = (n + ROWS_PER_BLOCK - 1) / ROWS_PER_BLOCK;
    ms_stats<<<g1, 256, 0, stream>>>(x, bidx, n, sum, sumsq, cnt);
    ms_norm<<<NORM_GRID, 256, 0, stream>>>(x, bidx, sum, sumsq, cnt, w, bias, out, n);
}

// Round 8
// 322.443 us; speedup vs baseline: 1.0979x; 1.0979x over previous
//
#include <hip/hip_runtime.h>

#define CC 128          // channels
#define BSEG 16         // segments
#define EPSV 1e-5f
#define ROWS_PER_BLOCK 512
#define NORM_GRID 2048

// Native clang vector (valid for __builtin_nontemporal_store, unlike HIP float4).
typedef float v4f __attribute__((ext_vector_type(4)));

// first index i in [0,n) with a[i] >= v   (a sorted ascending)
__device__ __forceinline__ int lower_bound_dev(const int* __restrict__ a, int n, int v)
{
    int lo = 0, hi = n;
    while (lo < hi) {
        const int mid = (lo + hi) >> 1;
        if (a[mid] < v) lo = mid + 1; else hi = mid;
    }
    return lo;
}

// ---------------------------------------------------------------------------
// Kernel 1: per-segment per-channel sum / sumsq.
// Block owns ROWS_PER_BLOCK contiguous rows, FORWARD traversal (leaves the
// tail of x freshest in L3 for the reverse-order normalize pass).
// Thread (tr,tq) = (row-lane 0..7, channel-quad 0..31); inner loop unrolled
// x2 (two independent dwordx4 loads in flight per thread).
// Uniform blocks (common; batch_idx sorted): LDS reduce + 256 atomics.
// Boundary blocks (<=15): flush-on-segment-change atomic path.
// Counts are NOT accumulated here: norm derives them exactly from the
// segment boundaries (binary search on the sorted batch_idx).
// ---------------------------------------------------------------------------
__global__ __launch_bounds__(256) void ms_stats(const float* __restrict__ x,
                                                const int* __restrict__ bidx,
                                                int n,
                                                float* __restrict__ sum,
                                                float* __restrict__ sumsq)
{
    const int r0 = blockIdx.x * ROWS_PER_BLOCK;
    if (r0 >= n) return;
    const int rend = min(r0 + ROWS_PER_BLOCK, n);
    const int tq = threadIdx.x & 31;   // channel quad 0..31
    const int tr = threadIdx.x >> 5;   // row lane 0..7

    const int seg_first = bidx[r0];
    const int seg_last  = bidx[rend - 1];

    v4f s = {0.f, 0.f, 0.f, 0.f};
    v4f q = {0.f, 0.f, 0.f, 0.f};

    if (seg_first == seg_last) {
        int r = r0 + tr;
        for (; r + 8 < rend; r += 16) {
            const v4f a = *reinterpret_cast<const v4f*>(x + (size_t)r * CC + tq * 4);
            const v4f b = *reinterpret_cast<const v4f*>(x + (size_t)(r + 8) * CC + tq * 4);
            s += a; q += a * a;
            s += b; q += b * b;
        }
        if (r < rend) {
            const v4f a = *reinterpret_cast<const v4f*>(x + (size_t)r * CC + tq * 4);
            s += a; q += a * a;
        }
        // LDS reduce of 8 row-lanes; layout [tr][slot][tq] is lane-consecutive.
        __shared__ float red[8][8][32];
        red[tr][0][tq] = s.x; red[tr][1][tq] = s.y; red[tr][2][tq] = s.z; red[tr][3][tq] = s.w;
        red[tr][4][tq] = q.x; red[tr][5][tq] = q.y; red[tr][6][tq] = q.z; red[tr][7][tq] = q.w;
        __syncthreads();
        const int j = threadIdx.x >> 5;   // slot 0..7 (0-3 sum, 4-7 sumsq)
        float acc = 0.f;
        #pragma unroll
        for (int k = 0; k < 8; ++k) acc += red[k][j][tq];
        const int ch = tq * 4 + (j & 3);
        atomicAdd(((j < 4) ? sum : sumsq) + seg_first * CC + ch, acc);
    } else {
        int cur = -1;
        for (int r = r0 + tr; r < rend; r += 8) {
            const int seg = bidx[r];
            if (seg != cur) {
                if (cur >= 0) {
                    float* sd = sum   + cur * CC + tq * 4;
                    float* qd = sumsq + cur * CC + tq * 4;
                    atomicAdd(sd + 0, s.x); atomicAdd(sd + 1, s.y);
                    atomicAdd(sd + 2, s.z); atomicAdd(sd + 3, s.w);
                    atomicAdd(qd + 0, q.x); atomicAdd(qd + 1, q.y);
                    atomicAdd(qd + 2, q.z); atomicAdd(qd + 3, q.w);
                    s = (v4f){0.f, 0.f, 0.f, 0.f};
                    q = (v4f){0.f, 0.f, 0.f, 0.f};
                }
                cur = seg;
            }
            const v4f a = *reinterpret_cast<const v4f*>(x + (size_t)r * CC + tq * 4);
            s += a; q += a * a;
        }
        if (cur >= 0) {
            float* sd = sum   + cur * CC + tq * 4;
            float* qd = sumsq + cur * CC + tq * 4;
            atomicAdd(sd + 0, s.x); atomicAdd(sd + 1, s.y);
            atomicAdd(sd + 2, s.z); atomicAdd(sd + 3, s.w);
            atomicAdd(qd + 0, q.x); atomicAdd(qd + 1, q.y);
            atomicAdd(qd + 2, q.z); atomicAdd(qd + 3, q.w);
        }
    }
}

// ---------------------------------------------------------------------------
// Kernel 2: normalize. R3 structure (reverse grid-stride sweep so the whole
// grid marches a compact descending window harvesting the L3-resident tail
// of x; finalize fused into LDS tables; NT stores for out). NEW vs R3:
// zero global loads on the critical path besides x itself — the segment id
// comes from 15 register compares against binary-searched boundaries, so
// LDS-table addresses are pure arithmetic and the compiler can issue loads
// for several iterations ahead. Work unit = 32B pair (2 x dwordx4).
// ---------------------------------------------------------------------------
__global__ __launch_bounds__(256) void ms_norm(const float* __restrict__ x,
                                               const int* __restrict__ bidx,
                                               const float* __restrict__ sum,
                                               const float* __restrict__ sumsq,
                                               const float* __restrict__ w,
                                               const float* __restrict__ bias,
                                               float* __restrict__ out,
                                               int n)
{
    __shared__ int sbs[BSEG + 1];
    __shared__ v4f s_scale[BSEG * 32];   // [seg][channel-quad]
    __shared__ v4f s_shift[BSEG * 32];

    if (threadIdx.x <= BSEG)
        sbs[threadIdx.x] = lower_bound_dev(bidx, n, (int)threadIdx.x);
    __syncthreads();

    for (int i = threadIdx.x; i < BSEG * CC; i += 256) {
        const int b = i >> 7;          // CC == 128
        const int c = i & (CC - 1);
        const float nn   = fmaxf((float)(sbs[b + 1] - sbs[b]), 1.0f);
        const float mean = sum[i] / nn;
        const float var  = fmaxf(sumsq[i] / nn - mean * mean, 0.0f);
        const float sc   = rsqrtf(var + EPSV) * w[c];
        reinterpret_cast<float*>(s_scale)[i] = sc;
        reinterpret_cast<float*>(s_shift)[i] = fmaf(-mean, sc, bias[c]);
    }
    __syncthreads();

    // Segment boundaries (rows) in registers: seg(r) = #{i : r >= rb[i]}.
    int rb[BSEG - 1];
    #pragma unroll
    for (int i = 0; i < BSEG - 1; ++i) rb[i] = sbs[i + 1];

    const int total = n * 16;                        // 32B pairs, 16M < 2^31
    const int T     = (int)(gridDim.x * blockDim.x); // pair stride

    // Descending sweep: compact window moves tail -> head (L3 harvest).
    for (int p = total - 1 - (int)(blockIdx.x * blockDim.x + threadIdx.x);
         p >= 0; p -= T) {
        const int r = p >> 4;
        int seg = 0;
        #pragma unroll
        for (int i = 0; i < BSEG - 1; ++i) seg += (r >= rb[i]);

        const v4f a = reinterpret_cast<const v4f*>(x)[2 * (size_t)p];
        const v4f b = reinterpret_cast<const v4f*>(x)[2 * (size_t)p + 1];
        const int ti = seg * 32 + (p & 15) * 2;
        const v4f sca = s_scale[ti], scb = s_scale[ti + 1];
        const v4f sha = s_shift[ti], shb = s_shift[ti + 1];
        v4f oa, ob;
        oa.x = fmaf(a.x, sca.x, sha.x); oa.y = fmaf(a.y, sca.y, sha.y);
        oa.z = fmaf(a.z, sca.z, sha.z); oa.w = fmaf(a.w, sca.w, sha.w);
        ob.x = fmaf(b.x, scb.x, shb.x); ob.y = fmaf(b.y, scb.y, shb.y);
        ob.z = fmaf(b.z, scb.z, shb.z); ob.w = fmaf(b.w, scb.w, shb.w);
        __builtin_nontemporal_store(oa, reinterpret_cast<v4f*>(out) + 2 * (size_t)p);
        __builtin_nontemporal_store(ob, reinterpret_cast<v4f*>(out) + 2 * (size_t)p + 1);
    }
}

// ---------------------------------------------------------------------------
extern "C" void kernel_launch(void* const* d_in, const int* in_sizes, int n_in,
                              void* d_out, int out_size, void* d_ws, size_t ws_size,
                              hipStream_t stream)
{
    const float* x    = (const float*)d_in[0];
    const int*   bidx = (const int*)d_in[1];
    const float* w    = (const float*)d_in[2];
    const float* bias = (const float*)d_in[3];
    float* out = (float*)d_out;
    const int n = in_sizes[1];   // number of rows (batch_idx length)

    // Workspace layout (floats): sum[B*C] | sumsq[B*C]
    float* ws    = (float*)d_ws;
    float* sum   = ws;
    float* sumsq = ws + BSEG * CC;

    // Zero the accumulators (ws is poisoned; must be replay-safe).
    (void)hipMemsetAsync(d_ws, 0, (size_t)(2 * BSEG * CC) * sizeof(float), stream);

    const int g1 = (n + ROWS_PER_BLOCK - 1) / ROWS_PER_BLOCK;
    ms_stats<<<g1, 256, 0, stream>>>(x, bidx, n, sum, sumsq);
    ms_norm<<<NORM_GRID, 256, 0, stream>>>(x, bidx, sum, sumsq, w, bias, out, n);
}